// Round 1
// baseline (9.526 us; speedup 1.0000x reference)
//
#include <hip/hip_runtime.h>
#include <math.h>

__device__ __forceinline__ float gelu_exact(float x) {
    // torch/jax exact GELU: 0.5*x*(1+erf(x/sqrt(2)))
    return 0.5f * x * (1.0f + erff(x * 0.70710678118654752440f));
}

__global__ void __launch_bounds__(64) clngcn_fused(
    const float* __restrict__ cli,
    const float* __restrict__ c1w, const float* __restrict__ c1b,
    const float* __restrict__ c2w, const float* __restrict__ c2b,
    const float* __restrict__ m1w1, const float* __restrict__ m1b1,
    const float* __restrict__ m1w2, const float* __restrict__ m1b2,
    const float* __restrict__ m2w1, const float* __restrict__ m2b1,
    const float* __restrict__ m2w2, const float* __restrict__ m2b2,
    const float* __restrict__ g1w, const float* __restrict__ g1b,
    const float* __restrict__ g2w, const float* __restrict__ g2b,
    float* __restrict__ out)
{
    const int t = threadIdx.x;        // 0..63, single wave
    const int i = t >> 3;             // row of the 8x8 element this lane owns
    const int j = t & 7;              // col
    const int k = t & 31;             // hidden unit within the MLP half
    const bool lo = (t < 32);         // lanes 0-31 -> MLP1, 32-63 -> MLP2

    // cli (8 floats) into registers — same addresses across lanes, broadcast-cached.
    float x[8];
    #pragma unroll
    for (int q = 0; q < 8; ++q) x[q] = cli[q];

    const float C1W = c1w[0], C1B = c1b[0];
    const float C2W = c2w[0], C2B = c2b[0];
    const float G1W = g1w[0], G1B = g1b[0];
    const float G2W = g2w[0], G2B = g2b[0];

    // ---- the two 8->32->8 MLPs, one hidden unit per lane ----
    const float* W1 = lo ? m1w1 : m2w1;   // (32,8) row-major
    const float* B1 = lo ? m1b1 : m2b1;
    const float* W2 = lo ? m1w2 : m2w2;   // (8,32) row-major
    const float* B2 = lo ? m1b2 : m2b2;

    float acc = B1[k];
    #pragma unroll
    for (int q = 0; q < 8; ++q) acc = fmaf(x[q], W1[k * 8 + q], acc);
    const float h = gelu_exact(acc);

    // Second layer: 8 outputs, butterfly-reduce the 32 partial products
    // within each half (xor 1,2,4,8,16 keeps lanes inside their half).
    float r[8];
    #pragma unroll
    for (int q = 0; q < 8; ++q) {
        float p = h * W2[q * 32 + k];
        p += __shfl_xor(p, 1);
        p += __shfl_xor(p, 2);
        p += __shfl_xor(p, 4);
        p += __shfl_xor(p, 8);
        p += __shfl_xor(p, 16);
        r[q] = p + B2[q];
    }
    // Exchange halves so every lane holds cli_ss[0..7] and cli_mm[0..7].
    float cs[8], cm[8];
    #pragma unroll
    for (int q = 0; q < 8; ++q) {
        const float o = __shfl_xor(r[q], 32);
        cs[q] = lo ? r[q] : o;   // cli_ss (MLP1 output)
        cm[q] = lo ? o : r[q];   // cli_mm (MLP2 output)
    }

    // ---- per-(i,j) score matrix element ----
    const float sigma_i = fmaf(x[i], C1W, C1B);
    const float sigma_j = fmaf(x[j], C1W, C1B);
    const float alpha_j = fmaf(x[j], C2W, C2B);
    const float seg_i   = fmaxf(fmaf(x[i], G1W, G1B), 0.0f);
    const float seg_j   = fmaxf(fmaf(x[j], G1W, G1B), 0.0f);

    // dot = sum_q cli_ss[q] * alpha[q]  (collapses (diag_cha@alpha_T)@alpha)
    float dot = 0.0f;
    #pragma unroll
    for (int q = 0; q < 8; ++q) dot = fmaf(cs[q], fmaf(x[q], C2W, C2B), dot);

    const float diag_cha = cm[i] * cs[j];
    const float s = fmaf(cm[i] * dot, alpha_j, diag_cha * (sigma_i * sigma_j));

    // softmax over axis=1 (rows i) for each column j: butterfly over xor 8,16,32
    float m = s;
    m = fmaxf(m, __shfl_xor(m, 8));
    m = fmaxf(m, __shfl_xor(m, 16));
    m = fmaxf(m, __shfl_xor(m, 32));
    const float e = expf(s - m);
    float den = e;
    den += __shfl_xor(den, 8);
    den += __shfl_xor(den, 16);
    den += __shfl_xor(den, 32);
    const float sim = e / den;

    // seg_similar[j] = sum_i seg[i] * sim[i][j] — same column butterfly
    float p = seg_i * sim;
    p += __shfl_xor(p, 8);
    p += __shfl_xor(p, 16);
    p += __shfl_xor(p, 32);

    if (t < 8) {   // lanes 0..7: i==0, j==t
        out[j] = fmaxf(fmaf(p, G2W, G2B), 0.0f) + seg_j;
    }
}

extern "C" void kernel_launch(void* const* d_in, const int* in_sizes, int n_in,
                              void* d_out, int out_size, void* d_ws, size_t ws_size,
                              hipStream_t stream) {
    (void)in_sizes; (void)n_in; (void)d_ws; (void)ws_size; (void)out_size;
    clngcn_fused<<<dim3(1), dim3(64), 0, stream>>>(
        (const float*)d_in[0],
        (const float*)d_in[1],  (const float*)d_in[2],
        (const float*)d_in[3],  (const float*)d_in[4],
        (const float*)d_in[5],  (const float*)d_in[6],
        (const float*)d_in[7],  (const float*)d_in[8],
        (const float*)d_in[9],  (const float*)d_in[10],
        (const float*)d_in[11], (const float*)d_in[12],
        (const float*)d_in[13], (const float*)d_in[14],
        (const float*)d_in[15], (const float*)d_in[16],
        (float*)d_out);
}

// Round 2
// 9.518 us; speedup vs baseline: 1.0008x; 1.0008x over previous
//
#include <hip/hip_runtime.h>
#include <math.h>

__device__ __forceinline__ float gelu_exact(float x) {
    // torch/jax exact GELU: 0.5*x*(1+erf(x/sqrt(2)))
    return 0.5f * x * (1.0f + erff(x * 0.70710678118654752440f));
}

__global__ void __launch_bounds__(64) clngcn_fused(
    const float* __restrict__ cli,
    const float* __restrict__ c1w, const float* __restrict__ c1b,
    const float* __restrict__ c2w, const float* __restrict__ c2b,
    const float* __restrict__ m1w1, const float* __restrict__ m1b1,
    const float* __restrict__ m1w2, const float* __restrict__ m1b2,
    const float* __restrict__ m2w1, const float* __restrict__ m2b1,
    const float* __restrict__ m2w2, const float* __restrict__ m2b2,
    const float* __restrict__ g1w, const float* __restrict__ g1b,
    const float* __restrict__ g2w, const float* __restrict__ g2b,
    float* __restrict__ out)
{
    const int t = threadIdx.x;        // 0..63, single wave
    const int i = t >> 3;             // row of the 8x8 element this lane owns
    const int j = t & 7;              // col
    const int k = t & 31;             // hidden unit within the MLP half
    const bool lo = (t < 32);         // lanes 0-31 -> MLP1, 32-63 -> MLP2

    // ---- vectorized input loads (all issued up front, independent) ----
    const float4 xa = *(const float4*)(cli);
    const float4 xb = *(const float4*)(cli + 4);
    const float x0 = xa.x, x1 = xa.y, x2 = xa.z, x3 = xa.w;
    const float x4 = xb.x, x5 = xb.y, x6 = xb.z, x7 = xb.w;
    const float x_own = __shfl(x0, 0) * 0.0f + ((const float*)cli)[j]; // x[j], per-lane coalesced
    // (the shfl(x0,0)*0 is dead; keep load simple:)

    const float C1W = c1w[0], C1B = c1b[0];
    const float C2W = c2w[0], C2B = c2b[0];
    const float G1W = g1w[0], G1B = g1b[0];
    const float G2W = g2w[0], G2B = g2b[0];

    // ---- the two 8->32->8 MLPs, one hidden unit per lane ----
    const float* W1 = lo ? m1w1 : m2w1;   // (32,8) row-major
    const float* B1 = lo ? m1b1 : m2b1;
    const float* W2 = lo ? m1w2 : m2w2;   // (8,32) row-major
    const float* B2 = lo ? m1b2 : m2b2;

    const float4 wa = *(const float4*)(W1 + k * 8);
    const float4 wb = *(const float4*)(W1 + k * 8 + 4);
    float acc = B1[k];
    acc = fmaf(x0, wa.x, acc); acc = fmaf(x1, wa.y, acc);
    acc = fmaf(x2, wa.z, acc); acc = fmaf(x3, wa.w, acc);
    acc = fmaf(x4, wb.x, acc); acc = fmaf(x5, wb.y, acc);
    acc = fmaf(x6, wb.z, acc); acc = fmaf(x7, wb.w, acc);
    const float h = gelu_exact(acc);

    // ---- layer 2: split-butterfly multi-reduce, 7 shuffles total ----
    // v[q] = h * W2[q,k]; reduce over the 32 lanes of each half.
    float v0 = h * W2[0 * 32 + k], v1e = h * W2[1 * 32 + k];
    float v2 = h * W2[2 * 32 + k], v3 = h * W2[3 * 32 + k];
    float v4 = h * W2[4 * 32 + k], v5 = h * W2[5 * 32 + k];
    float v6 = h * W2[6 * 32 + k], v7 = h * W2[7 * 32 + k];

    const bool b0 = (k & 1), b1 = (k & 2), b2 = (k & 4);
    // step xor 1: keep outputs {4..7} if bit0 else {0..3}
    float w0 = (b0 ? v4 : v0) + __shfl_xor(b0 ? v0 : v4, 1);
    float w1 = (b0 ? v5 : v1e) + __shfl_xor(b0 ? v1e : v5, 1);
    float w2 = (b0 ? v6 : v2) + __shfl_xor(b0 ? v2 : v6, 1);
    float w3 = (b0 ? v7 : v3) + __shfl_xor(b0 ? v3 : v7, 1);
    // step xor 2
    float u0 = (b1 ? w2 : w0) + __shfl_xor(b1 ? w0 : w2, 2);
    float u1 = (b1 ? w3 : w1) + __shfl_xor(b1 ? w1 : w3, 2);
    // step xor 4
    float tv = (b2 ? u1 : u0) + __shfl_xor(b2 ? u0 : u1, 4);
    // pure reduce over remaining lane bits 3,4
    tv += __shfl_xor(tv, 8);
    tv += __shfl_xor(tv, 16);
    // lane k now holds output qidx = 4*bit0 + 2*bit1 + bit2 (full sum over half)
    const int qidx = ((k & 1) << 2) | (k & 2) | ((k >> 2) & 1);
    const float val = tv + B2[qidx];

    // ---- broadcast cli_ss (lower half) to all lanes; lane map l(q)={0,4,2,6,1,5,3,7}
    const float cs0g = __shfl(val, 0), cs1g = __shfl(val, 4);
    const float cs2g = __shfl(val, 2), cs3g = __shfl(val, 6);
    const float cs4g = __shfl(val, 1), cs5g = __shfl(val, 5);
    const float cs6g = __shfl(val, 3), cs7g = __shfl(val, 7);
    // per-lane needed elements
    const int lj = ((j >> 2) & 1) | (j & 2) | ((j & 1) << 2);
    const int li = ((i >> 2) & 1) | (i & 2) | ((i & 1) << 2);
    const float cs_j = __shfl(val, lj);        // cli_ss[j]
    const float cm_i = __shfl(val, 32 + li);   // cli_mm[i]
    const float x_i  = __shfl(x_own, i);       // cli[i]

    // ---- per-(i,j) score matrix element ----
    const float sigma_i = fmaf(x_i, C1W, C1B);
    const float sigma_j = fmaf(x_own, C1W, C1B);
    const float alpha_j = fmaf(x_own, C2W, C2B);
    const float seg_i   = fmaxf(fmaf(x_i, G1W, G1B), 0.0f);
    const float seg_j   = fmaxf(fmaf(x_own, G1W, G1B), 0.0f);

    // dot = sum_q cli_ss[q] * alpha[q]
    float dot = 0.0f;
    dot = fmaf(cs0g, fmaf(x0, C2W, C2B), dot);
    dot = fmaf(cs1g, fmaf(x1, C2W, C2B), dot);
    dot = fmaf(cs2g, fmaf(x2, C2W, C2B), dot);
    dot = fmaf(cs3g, fmaf(x3, C2W, C2B), dot);
    dot = fmaf(cs4g, fmaf(x4, C2W, C2B), dot);
    dot = fmaf(cs5g, fmaf(x5, C2W, C2B), dot);
    dot = fmaf(cs6g, fmaf(x6, C2W, C2B), dot);
    dot = fmaf(cs7g, fmaf(x7, C2W, C2B), dot);

    const float diag_cha = cm_i * cs_j;
    const float s = fmaf(cm_i * dot, alpha_j, diag_cha * (sigma_i * sigma_j));

    // softmax over axis=1 (rows i) per column j: butterfly over xor 8,16,32
    float m = s;
    m = fmaxf(m, __shfl_xor(m, 8));
    m = fmaxf(m, __shfl_xor(m, 16));
    m = fmaxf(m, __shfl_xor(m, 32));
    const float e = expf(s - m);
    float den = e;
    den += __shfl_xor(den, 8);
    den += __shfl_xor(den, 16);
    den += __shfl_xor(den, 32);
    const float sim = e / den;

    // seg_similar[j] = sum_i seg[i] * sim[i][j]
    float p = seg_i * sim;
    p += __shfl_xor(p, 8);
    p += __shfl_xor(p, 16);
    p += __shfl_xor(p, 32);

    if (t < 8) {   // lanes 0..7: j==t
        out[j] = fmaxf(fmaf(p, G2W, G2B), 0.0f) + seg_j;
    }
}

extern "C" void kernel_launch(void* const* d_in, const int* in_sizes, int n_in,
                              void* d_out, int out_size, void* d_ws, size_t ws_size,
                              hipStream_t stream) {
    (void)in_sizes; (void)n_in; (void)d_ws; (void)ws_size; (void)out_size;
    clngcn_fused<<<dim3(1), dim3(64), 0, stream>>>(
        (const float*)d_in[0],
        (const float*)d_in[1],  (const float*)d_in[2],
        (const float*)d_in[3],  (const float*)d_in[4],
        (const float*)d_in[5],  (const float*)d_in[6],
        (const float*)d_in[7],  (const float*)d_in[8],
        (const float*)d_in[9],  (const float*)d_in[10],
        (const float*)d_in[11], (const float*)d_in[12],
        (const float*)d_in[13], (const float*)d_in[14],
        (const float*)d_in[15], (const float*)d_in[16],
        (float*)d_out);
}